// Round 6
// baseline (177.613 us; speedup 1.0000x reference)
//
#include <hip/hip_runtime.h>
#include <math.h>

#define B_ 8
#define T_ 2048
#define C_ 1024
#define H_ 128

#define TQA 32           // q rows per attention block (2 row-groups x 16)
#define TKA 32           // k/v rows per tile

#define BM 128
#define BN 128
#define BK 64

typedef __attribute__((ext_vector_type(8))) short s16x8;
typedef __attribute__((ext_vector_type(4))) short s16x4;
typedef __attribute__((ext_vector_type(4))) float f32x4;
typedef __attribute__((ext_vector_type(8))) _Float16 f16x8;

__device__ __forceinline__ short f2bf(float f) {
    unsigned u = __float_as_uint(f);
    u += 0x7fffu + ((u >> 16) & 1u);       // RNE
    return (short)(u >> 16);
}
__device__ __forceinline__ float bf2f(short s) {
    return __uint_as_float(((unsigned)(unsigned short)s) << 16);
}

// ---------------------------------------------------------------------------
// Kernel 0: W prep — transpose W[k][h] (q,k,v) into Wt[n][k] hi/lo bf16.
// ---------------------------------------------------------------------------
__global__ __launch_bounds__(256) void wprep(
    const float* __restrict__ Wq, const float* __restrict__ Wk,
    const float* __restrict__ Wv,
    short* __restrict__ Wth, short* __restrict__ Wtl)
{
    const int n   = blockIdx.x;           // 0..383
    const int mat = n >> 7;
    const int h   = n & 127;
    const float* W = (mat == 0) ? Wq : (mat == 1) ? Wk : Wv;
    for (int k = threadIdx.x; k < C_; k += 256) {
        const float w = W[(size_t)k * H_ + h];
        const short hi = f2bf(w);
        Wth[(size_t)n * C_ + k] = hi;
        Wtl[(size_t)n * C_ + k] = f2bf(w - bf2f(hi));
    }
}

// ---------------------------------------------------------------------------
// Kernel 1: 3-term hi/lo bf16 MFMA GEMM; epilogue emits fp16 q/k/v.
// ---------------------------------------------------------------------------
__global__ __launch_bounds__(256, 2) void gemm_proj(
    const float* __restrict__ x,
    const short* __restrict__ Wth, const short* __restrict__ Wtl,
    const float* __restrict__ bq, const float* __restrict__ bk,
    const float* __restrict__ bv,
    _Float16* __restrict__ qg, _Float16* __restrict__ kg,
    _Float16* __restrict__ vg)
{
    __shared__ short Ah[BM * BK];
    __shared__ short Al[BM * BK];
    __shared__ short Bh[BN * BK];
    __shared__ short Bl[BN * BK];

    const int tid  = threadIdx.x;
    const int my   = blockIdx.y;
    const long m0  = (long)blockIdx.x * BM;
    const int lane = tid & 63;
    const int w    = tid >> 6;
    const int wr   = w >> 1, wc = w & 1;
    const int lg   = lane >> 4, lc = lane & 15;

    float4 xr[8];

    #define LOAD_X(k0)                                                        \
        _Pragma("unroll")                                                     \
        for (int it = 0; it < 8; ++it) {                                      \
            const int i  = tid + it * 256;                                    \
            const int r  = i >> 4;                                            \
            const int k4 = i & 15;                                            \
            xr[it] = *(const float4*)&x[(m0 + r) * C_ + (k0) + k4 * 4];       \
        }

    #define STORE_LDS(k0)                                                     \
        _Pragma("unroll")                                                     \
        for (int it = 0; it < 8; ++it) {                                      \
            const int i  = tid + it * 256;                                    \
            const int r  = i >> 4;                                            \
            const int k4 = i & 15;                                            \
            s16x4 hi4, lo4;                                                   \
            _Pragma("unroll")                                                 \
            for (int j = 0; j < 4; ++j) {                                     \
                const float f = ((const float*)&xr[it])[j];                   \
                const short h8 = f2bf(f);                                     \
                hi4[j] = h8; lo4[j] = f2bf(f - bf2f(h8));                     \
            }                                                                 \
            const int off = r * 64 + (((k4 >> 1) ^ (r & 7)) << 3)             \
                          + ((k4 & 1) << 2);                                  \
            *(s16x4*)&Ah[off] = hi4;                                          \
            *(s16x4*)&Al[off] = lo4;                                          \
        }                                                                     \
        _Pragma("unroll")                                                     \
        for (int it = 0; it < 4; ++it) {                                      \
            const int i = tid + it * 256;                                     \
            const int r = i >> 3;                                             \
            const int s = i & 7;                                              \
            const size_t g = (size_t)(my * BN + r) * C_ + (k0) + s * 8;       \
            const int off = r * 64 + ((s ^ (r & 7)) << 3);                    \
            *(s16x8*)&Bh[off] = *(const s16x8*)&Wth[g];                       \
            *(s16x8*)&Bl[off] = *(const s16x8*)&Wtl[g];                       \
        }

    f32x4 acc[4][4];
    #pragma unroll
    for (int m = 0; m < 4; ++m)
        #pragma unroll
        for (int n = 0; n < 4; ++n) acc[m][n] = (f32x4){0.f, 0.f, 0.f, 0.f};

    LOAD_X(0);
    STORE_LDS(0);
    __syncthreads();

    for (int kt = 0; kt < C_ / BK; ++kt) {
        if (kt < C_ / BK - 1) LOAD_X((kt + 1) * BK);

        #pragma unroll
        for (int kc = 0; kc < 2; ++kc) {
            s16x8 afh[4], afl[4], bfh[4], bfl[4];
            #pragma unroll
            for (int m = 0; m < 4; ++m) {
                const int r = wr * 64 + m * 16 + lc;
                const int off = r * 64 + ((((kc << 2) + lg) ^ (r & 7)) << 3);
                afh[m] = *(const s16x8*)&Ah[off];
                afl[m] = *(const s16x8*)&Al[off];
            }
            #pragma unroll
            for (int n = 0; n < 4; ++n) {
                const int r = wc * 64 + n * 16 + lc;
                const int off = r * 64 + ((((kc << 2) + lg) ^ (r & 7)) << 3);
                bfh[n] = *(const s16x8*)&Bh[off];
                bfl[n] = *(const s16x8*)&Bl[off];
            }
            #pragma unroll
            for (int m = 0; m < 4; ++m)
                #pragma unroll
                for (int n = 0; n < 4; ++n) {
                    acc[m][n] = __builtin_amdgcn_mfma_f32_16x16x32_bf16(afh[m], bfh[n], acc[m][n], 0, 0, 0);
                    acc[m][n] = __builtin_amdgcn_mfma_f32_16x16x32_bf16(afh[m], bfl[n], acc[m][n], 0, 0, 0);
                    acc[m][n] = __builtin_amdgcn_mfma_f32_16x16x32_bf16(afl[m], bfh[n], acc[m][n], 0, 0, 0);
                }
        }
        __syncthreads();
        if (kt < C_ / BK - 1) {
            STORE_LDS((kt + 1) * BK);
            __syncthreads();
        }
    }

    const float* bias = (my == 0) ? bq : (my == 1) ? bk : bv;
    _Float16* og = (my == 0) ? qg : (my == 1) ? kg : vg;

    #pragma unroll
    for (int n = 0; n < 4; ++n) {
        const int h = wc * 64 + n * 16 + lc;
        const float bv_ = bias[h];
        #pragma unroll
        for (int m = 0; m < 4; ++m) {
            #pragma unroll
            for (int rr = 0; rr < 4; ++rr) {
                const long row = m0 + wr * 64 + m * 16 + lg * 4 + rr;
                og[(size_t)row * H_ + h] = (_Float16)(acc[m][n][rr] + bv_);
            }
        }
    }
}

// ---------------------------------------------------------------------------
// Kernel 1b: vtrans — vg [B][T][H] -> vtg [B][H][T] (fp16 bits via short).
// ---------------------------------------------------------------------------
__global__ __launch_bounds__(256) void vtrans(
    const short* __restrict__ vh, short* __restrict__ vtg)
{
    __shared__ short tbuf[64][72];
    const int b  = blockIdx.z;
    const int t0 = blockIdx.x * 64;
    const int h0 = blockIdx.y * 64;
    const int tid = threadIdx.x;
    const size_t bo  = (size_t)b * T_ * H_;
    const size_t vbo = (size_t)b * H_ * T_;

    #pragma unroll
    for (int it = 0; it < 2; ++it) {
        const int u = tid + it * 256;
        const int r = u >> 3, c8 = u & 7;
        *(s16x8*)&tbuf[r][c8 * 8] =
            *(const s16x8*)&vh[bo + (size_t)(t0 + r) * H_ + h0 + c8 * 8];
    }
    __syncthreads();
    #pragma unroll
    for (int it = 0; it < 2; ++it) {
        const int u = tid + it * 256;
        const int t8 = u >> 6, hr = u & 63;
        s16x8 v;
        #pragma unroll
        for (int j = 0; j < 8; ++j) v[j] = tbuf[t8 * 8 + j][hr];
        *(s16x8*)&vtg[vbo + (size_t)(h0 + hr) * T_ + t0 + t8 * 8] = v;
    }
}

// ---------------------------------------------------------------------------
// Kernel 2: causal flash attention v4 — fp16 MFMA, single-term.
// 1D grid 512 blocks (global LPT: wg>>3 gives tile rank, wg&7 = batch).
// 256 threads = 4 waves: rg=w>>1 (16 q rows), kp=w&1 (key-tile parity).
// LDS 37 KB: K[2] + Vt[2] + Pw, combine buffers aliased -> 4 blocks/CU.
// ---------------------------------------------------------------------------
__global__ __launch_bounds__(256, 4) void attn_v4(
    const _Float16* __restrict__ qg, const _Float16* __restrict__ kg,
    const _Float16* __restrict__ vtg, float* __restrict__ out)
{
    __shared__ __align__(16) char smem[37376];
    _Float16* Kh = (_Float16*)smem;              // [2][32*128]  16 KB
    _Float16* Vt = (_Float16*)(smem + 16384);    // [2][128*32]  16 KB
    _Float16* Pw = (_Float16*)(smem + 32768);    // [4][16*36]   4.6 KB
    float* Ocmb  = (float*)smem;                 // [2][64][33]  (aliased)
    float* Mcmb  = (float*)(smem + 16896);       // [2][64][8]   (aliased)

    const int tid  = threadIdx.x;
    const int lane = tid & 63;
    const int w    = tid >> 6;
    const int rg   = w >> 1;
    const int kp   = w & 1;
    const int lg   = lane >> 4;
    const int lc   = lane & 15;
    const int wg   = blockIdx.x;           // 0..511
    const int tile = 63 - (wg >> 3);       // global LPT
    const int b    = wg & 7;
    const int t0   = tile * TQA;

    const size_t bo  = (size_t)b * T_ * H_;
    const size_t vbo = (size_t)b * H_ * T_;

    // ---- Q fragments (A-layout: row=lc, k=lg*8+j per 32-chunk) ----
    f16x8 qf[4];
    {
        const size_t rbase = bo + (size_t)(t0 + rg * 16 + lc) * H_;
        #pragma unroll
        for (int kc = 0; kc < 4; ++kc)
            qf[kc] = *(const f16x8*)(qg + rbase + kc * 32 + lg * 8);
    }

    f32x4 Oacc[8];
    #pragma unroll
    for (int ht = 0; ht < 8; ++ht) Oacc[ht] = (f32x4){0.f, 0.f, 0.f, 0.f};
    float m_run[4] = {-INFINITY, -INFINITY, -INFINITY, -INFINITY};
    float l_run[4] = {0.f, 0.f, 0.f, 0.f};

    const int nt = tile + 1;
    const int R  = (nt + 1) >> 1;

    f16x8 pf[8];    // prefetch: K 16 KB + V 16 KB per round / 256 thr

    // 8 chunks/thread: g = tid + it*256; arr = g>>10 (0=K,1=V);
    // cid = g&1023; buf = cid>>9 (parity); idx = cid&511.
    #define ISSUE_LOADS(rr_)                                                  \
        _Pragma("unroll")                                                     \
        for (int it = 0; it < 8; ++it) {                                      \
            const int g   = tid + it * 256;                                   \
            const int arr = g >> 10;                                          \
            const int cid = g & 1023;                                         \
            const int buf = cid >> 9;                                         \
            const int idx = cid & 511;                                        \
            int kt_ = 2 * (rr_) + buf; if (kt_ >= nt) kt_ = nt - 1;           \
            const int s0_ = kt_ * TKA;                                        \
            if (arr == 0) {                                                   \
                const int key = idx >> 4, hc = idx & 15;                      \
                pf[it] = *(const f16x8*)(kg + bo                              \
                          + (size_t)(s0_ + key) * H_ + hc * 8);               \
            } else {                                                          \
                const int hh = idx >> 2, k4 = idx & 3;                        \
                pf[it] = *(const f16x8*)(vtg + vbo + (size_t)hh * T_          \
                          + s0_ + k4 * 8);                                    \
            }                                                                 \
        }

    #define WRITE_LDS()                                                       \
        _Pragma("unroll")                                                     \
        for (int it = 0; it < 8; ++it) {                                      \
            const int g   = tid + it * 256;                                   \
            const int arr = g >> 10;                                          \
            const int cid = g & 1023;                                         \
            const int buf = cid >> 9;                                         \
            const int idx = cid & 511;                                        \
            if (arr == 0) {                                                   \
                const int key = idx >> 4, hc = idx & 15;                      \
                const int off = key * 128 + ((hc ^ (key & 7)) << 3);          \
                *(f16x8*)&Kh[buf * 4096 + off] = pf[it];                      \
            } else {                                                          \
                const int hh = idx >> 2, k4 = idx & 3;                        \
                const int off = hh * 32 + ((((hh >> 1) ^ k4) & 3) << 3);      \
                *(f16x8*)&Vt[buf * 4096 + off] = pf[it];                      \
            }                                                                 \
        }

    ISSUE_LOADS(0);

    for (int r = 0; r < R; ++r) {
        WRITE_LDS();                      // implicit vmcnt wait on pf
        __syncthreads();
        if (r + 1 < R) ISSUE_LOADS(r + 1);

        const int kt = 2 * r + kp;
        if (kt < nt) {
            const int s0 = kt * TKA;

            // ---- S = Q K^T : 2 col-tiles x 4 k-chunks, single fp16 term ----
            f32x4 sfr[2];
            sfr[0] = (f32x4){0.f, 0.f, 0.f, 0.f};
            sfr[1] = (f32x4){0.f, 0.f, 0.f, 0.f};
            #pragma unroll
            for (int kc = 0; kc < 4; ++kc) {
                #pragma unroll
                for (int ct = 0; ct < 2; ++ct) {
                    const int key = ct * 16 + lc;
                    const int hc  = kc * 4 + lg;
                    const int off = key * 128 + ((hc ^ (key & 7)) << 3);
                    const f16x8 bh = *(const f16x8*)&Kh[kp * 4096 + off];
                    sfr[ct] = __builtin_amdgcn_mfma_f32_16x16x32_f16(qf[kc], bh, sfr[ct], 0, 0, 0);
                }
            }

            // ---- causal mask ----
            #pragma unroll
            for (int ct = 0; ct < 2; ++ct) {
                const int key_g = s0 + ct * 16 + lc;
                #pragma unroll
                for (int rr = 0; rr < 4; ++rr) {
                    const int row_g = t0 + rg * 16 + lg * 4 + rr;
                    if (key_g > row_g) sfr[ct][rr] = -INFINITY;
                }
            }

            // ---- online softmax (16-lane shfl_xor reduce) ----
            float mx[4];
            #pragma unroll
            for (int rr = 0; rr < 4; ++rr)
                mx[rr] = fmaxf(sfr[0][rr], sfr[1][rr]);
            #pragma unroll
            for (int d = 1; d < 16; d <<= 1)
                #pragma unroll
                for (int rr = 0; rr < 4; ++rr)
                    mx[rr] = fmaxf(mx[rr], __shfl_xor(mx[rr], d, 64));

            float sc[4], sum[4];
            #pragma unroll
            for (int rr = 0; rr < 4; ++rr) {
                const float mnew = fmaxf(m_run[rr], mx[rr]);
                sc[rr] = __expf(m_run[rr] - mnew);
                m_run[rr] = mnew;
                sum[rr] = 0.f;
            }
            #pragma unroll
            for (int ct = 0; ct < 2; ++ct)
                #pragma unroll
                for (int rr = 0; rr < 4; ++rr) {
                    const float p = __expf(sfr[ct][rr] - m_run[rr]);
                    sfr[ct][rr] = p;
                    sum[rr] += p;
                }
            #pragma unroll
            for (int d = 1; d < 16; d <<= 1)
                #pragma unroll
                for (int rr = 0; rr < 4; ++rr)
                    sum[rr] += __shfl_xor(sum[rr], d, 64);
            #pragma unroll
            for (int rr = 0; rr < 4; ++rr)
                l_run[rr] = l_run[rr] * sc[rr] + sum[rr];

            #pragma unroll
            for (int ht = 0; ht < 8; ++ht)
                #pragma unroll
                for (int rr = 0; rr < 4; ++rr) Oacc[ht][rr] *= sc[rr];

            // ---- P (fp16) to per-wave LDS, then PV ----
            #pragma unroll
            for (int ct = 0; ct < 2; ++ct)
                #pragma unroll
                for (int rr = 0; rr < 4; ++rr)
                    Pw[w * 576 + (lg * 4 + rr) * 36 + ct * 16 + lc] =
                        (_Float16)sfr[ct][rr];

            const f16x8 pa = *(const f16x8*)&Pw[w * 576 + lc * 36 + lg * 8];
            #pragma unroll
            for (int ht = 0; ht < 8; ++ht) {
                const int h = ht * 16 + lc;
                const int off = h * 32 + ((((h >> 1) ^ lg) & 3) << 3);
                const f16x8 vb = *(const f16x8*)&Vt[kp * 4096 + off];
                Oacc[ht] = __builtin_amdgcn_mfma_f32_16x16x32_f16(pa, vb, Oacc[ht], 0, 0, 0);
            }
        }
        __syncthreads();
    }

    // ---- pair combine (combine buffers alias dead K/V LDS) ----
    if (kp == 1) {
        float* dst = Ocmb + (size_t)(rg * 64 + lane) * 33;
        #pragma unroll
        for (int ht = 0; ht < 8; ++ht)
            #pragma unroll
            for (int rr = 0; rr < 4; ++rr) dst[ht * 4 + rr] = Oacc[ht][rr];
        float* mm = Mcmb + (size_t)(rg * 64 + lane) * 8;
        #pragma unroll
        for (int rr = 0; rr < 4; ++rr) {
            mm[rr]     = m_run[rr];
            mm[4 + rr] = l_run[rr];
        }
    }
    __syncthreads();
    if (kp == 0) {
        const float* mm = Mcmb + (size_t)(rg * 64 + lane) * 8;
        float a0[4], a1[4], inv[4];
        #pragma unroll
        for (int rr = 0; rr < 4; ++rr) {
            const float m1 = mm[rr];
            const float l1 = mm[4 + rr];
            const float M  = fmaxf(m_run[rr], m1);
            a0[rr] = __expf(m_run[rr] - M);
            a1[rr] = __expf(m1 - M);
            inv[rr] = 1.f / (l_run[rr] * a0[rr] + l1 * a1[rr]);
        }
        const float* src = Ocmb + (size_t)(rg * 64 + lane) * 33;
        float* ob = out + bo + (size_t)(t0 + rg * 16) * H_;
        #pragma unroll
        for (int ht = 0; ht < 8; ++ht)
            #pragma unroll
            for (int rr = 0; rr < 4; ++rr) {
                const float val = (Oacc[ht][rr] * a0[rr]
                                 + src[ht * 4 + rr] * a1[rr]) * inv[rr];
                ob[(size_t)(lg * 4 + rr) * H_ + ht * 16 + lc] = val;
            }
    }
}

// ---------------------------------------------------------------------------
extern "C" void kernel_launch(void* const* d_in, const int* in_sizes, int n_in,
                              void* d_out, int out_size, void* d_ws, size_t ws_size,
                              hipStream_t stream)
{
    const float* x  = (const float*)d_in[0];
    const float* Wq = (const float*)d_in[1];
    const float* bq = (const float*)d_in[2];
    const float* Wk = (const float*)d_in[3];
    const float* bk = (const float*)d_in[4];
    const float* Wv = (const float*)d_in[5];
    const float* bv = (const float*)d_in[6];
    float* out = (float*)d_out;

    const size_t SZ = (size_t)B_ * T_ * H_;     // 2M elems
    _Float16* qg = (_Float16*)d_ws;
    _Float16* kg = qg + SZ;
    _Float16* vg = kg + SZ;
    short* Wth   = (short*)(vg + SZ);            // [384][1024] bf16
    short* Wtl   = Wth + (size_t)384 * C_;
    _Float16* vtg = (_Float16*)(Wtl + (size_t)384 * C_);   // [B][H][T]

    wprep<<<dim3(384), dim3(256), 0, stream>>>(Wq, Wk, Wv, Wth, Wtl);
    gemm_proj<<<dim3(B_ * T_ / BM, 3), dim3(256), 0, stream>>>(
        x, Wth, Wtl, bq, bk, bv, qg, kg, vg);
    vtrans<<<dim3(T_ / 64, H_ / 64, B_), dim3(256), 0, stream>>>(
        (const short*)vg, (short*)vtg);
    attn_v4<<<dim3(512), dim3(256), 0, stream>>>(qg, kg, vtg, out);
}

// Round 7
// 103.435 us; speedup vs baseline: 1.7171x; 1.7171x over previous
//
#include <hip/hip_runtime.h>
#include <math.h>

#define B_ 8
#define T_ 2048
#define C_ 1024
#define H_ 128

#define TQA 32           // q rows per attention block (2 row-groups x 16)

#define BM 128
#define BN 128
#define BK 64

typedef __attribute__((ext_vector_type(8))) short s16x8;
typedef __attribute__((ext_vector_type(4))) short s16x4;
typedef __attribute__((ext_vector_type(4))) float f32x4;
typedef __attribute__((ext_vector_type(8))) _Float16 f16x8;
typedef __attribute__((ext_vector_type(4))) _Float16 f16x4;

__device__ __forceinline__ short f2bf(float f) {
    unsigned u = __float_as_uint(f);
    u += 0x7fffu + ((u >> 16) & 1u);       // RNE
    return (short)(u >> 16);
}
__device__ __forceinline__ float bf2f(short s) {
    return __uint_as_float(((unsigned)(unsigned short)s) << 16);
}

// ---------------------------------------------------------------------------
// Kernel 0: W prep — transpose W[k][h] (q,k,v) into Wt[n][k] hi/lo bf16.
// ---------------------------------------------------------------------------
__global__ __launch_bounds__(256) void wprep(
    const float* __restrict__ Wq, const float* __restrict__ Wk,
    const float* __restrict__ Wv,
    short* __restrict__ Wth, short* __restrict__ Wtl)
{
    const int n   = blockIdx.x;           // 0..383
    const int mat = n >> 7;
    const int h   = n & 127;
    const float* W = (mat == 0) ? Wq : (mat == 1) ? Wk : Wv;
    for (int k = threadIdx.x; k < C_; k += 256) {
        const float w = W[(size_t)k * H_ + h];
        const short hi = f2bf(w);
        Wth[(size_t)n * C_ + k] = hi;
        Wtl[(size_t)n * C_ + k] = f2bf(w - bf2f(hi));
    }
}

// ---------------------------------------------------------------------------
// Kernel 1: 3-term hi/lo bf16 MFMA GEMM; epilogue emits fp16 q/k/v.
// ---------------------------------------------------------------------------
__global__ __launch_bounds__(256, 2) void gemm_proj(
    const float* __restrict__ x,
    const short* __restrict__ Wth, const short* __restrict__ Wtl,
    const float* __restrict__ bq, const float* __restrict__ bk,
    const float* __restrict__ bv,
    _Float16* __restrict__ qg, _Float16* __restrict__ kg,
    _Float16* __restrict__ vg)
{
    __shared__ short Ah[BM * BK];
    __shared__ short Al[BM * BK];
    __shared__ short Bh[BN * BK];
    __shared__ short Bl[BN * BK];

    const int tid  = threadIdx.x;
    const int my   = blockIdx.y;
    const long m0  = (long)blockIdx.x * BM;
    const int lane = tid & 63;
    const int w    = tid >> 6;
    const int wr   = w >> 1, wc = w & 1;
    const int lg   = lane >> 4, lc = lane & 15;

    float4 xr[8];

    #define LOAD_X(k0)                                                        \
        _Pragma("unroll")                                                     \
        for (int it = 0; it < 8; ++it) {                                      \
            const int i  = tid + it * 256;                                    \
            const int r  = i >> 4;                                            \
            const int k4 = i & 15;                                            \
            xr[it] = *(const float4*)&x[(m0 + r) * C_ + (k0) + k4 * 4];       \
        }

    #define STORE_LDS(k0)                                                     \
        _Pragma("unroll")                                                     \
        for (int it = 0; it < 8; ++it) {                                      \
            const int i  = tid + it * 256;                                    \
            const int r  = i >> 4;                                            \
            const int k4 = i & 15;                                            \
            s16x4 hi4, lo4;                                                   \
            _Pragma("unroll")                                                 \
            for (int j = 0; j < 4; ++j) {                                     \
                const float f = ((const float*)&xr[it])[j];                   \
                const short h8 = f2bf(f);                                     \
                hi4[j] = h8; lo4[j] = f2bf(f - bf2f(h8));                     \
            }                                                                 \
            const int off = r * 64 + (((k4 >> 1) ^ (r & 7)) << 3)             \
                          + ((k4 & 1) << 2);                                  \
            *(s16x4*)&Ah[off] = hi4;                                          \
            *(s16x4*)&Al[off] = lo4;                                          \
        }                                                                     \
        _Pragma("unroll")                                                     \
        for (int it = 0; it < 4; ++it) {                                      \
            const int i = tid + it * 256;                                     \
            const int r = i >> 3;                                             \
            const int s = i & 7;                                              \
            const size_t g = (size_t)(my * BN + r) * C_ + (k0) + s * 8;       \
            const int off = r * 64 + ((s ^ (r & 7)) << 3);                    \
            *(s16x8*)&Bh[off] = *(const s16x8*)&Wth[g];                       \
            *(s16x8*)&Bl[off] = *(const s16x8*)&Wtl[g];                       \
        }

    f32x4 acc[4][4];
    #pragma unroll
    for (int m = 0; m < 4; ++m)
        #pragma unroll
        for (int n = 0; n < 4; ++n) acc[m][n] = (f32x4){0.f, 0.f, 0.f, 0.f};

    LOAD_X(0);
    STORE_LDS(0);
    __syncthreads();

    for (int kt = 0; kt < C_ / BK; ++kt) {
        if (kt < C_ / BK - 1) LOAD_X((kt + 1) * BK);

        #pragma unroll
        for (int kc = 0; kc < 2; ++kc) {
            s16x8 afh[4], afl[4], bfh[4], bfl[4];
            #pragma unroll
            for (int m = 0; m < 4; ++m) {
                const int r = wr * 64 + m * 16 + lc;
                const int off = r * 64 + ((((kc << 2) + lg) ^ (r & 7)) << 3);
                afh[m] = *(const s16x8*)&Ah[off];
                afl[m] = *(const s16x8*)&Al[off];
            }
            #pragma unroll
            for (int n = 0; n < 4; ++n) {
                const int r = wc * 64 + n * 16 + lc;
                const int off = r * 64 + ((((kc << 2) + lg) ^ (r & 7)) << 3);
                bfh[n] = *(const s16x8*)&Bh[off];
                bfl[n] = *(const s16x8*)&Bl[off];
            }
            #pragma unroll
            for (int m = 0; m < 4; ++m)
                #pragma unroll
                for (int n = 0; n < 4; ++n) {
                    acc[m][n] = __builtin_amdgcn_mfma_f32_16x16x32_bf16(afh[m], bfh[n], acc[m][n], 0, 0, 0);
                    acc[m][n] = __builtin_amdgcn_mfma_f32_16x16x32_bf16(afh[m], bfl[n], acc[m][n], 0, 0, 0);
                    acc[m][n] = __builtin_amdgcn_mfma_f32_16x16x32_bf16(afl[m], bfh[n], acc[m][n], 0, 0, 0);
                }
        }
        __syncthreads();
        if (kt < C_ / BK - 1) {
            STORE_LDS((kt + 1) * BK);
            __syncthreads();
        }
    }

    const float* bias = (my == 0) ? bq : (my == 1) ? bk : bv;
    _Float16* og = (my == 0) ? qg : (my == 1) ? kg : vg;

    #pragma unroll
    for (int n = 0; n < 4; ++n) {
        const int h = wc * 64 + n * 16 + lc;
        const float bv_ = bias[h];
        #pragma unroll
        for (int m = 0; m < 4; ++m) {
            #pragma unroll
            for (int rr = 0; rr < 4; ++rr) {
                const long row = m0 + wr * 64 + m * 16 + lg * 4 + rr;
                og[(size_t)row * H_ + h] = (_Float16)(acc[m][n][rr] + bv_);
            }
        }
    }
}

// ---------------------------------------------------------------------------
// Kernel 1b: vtrans — vg [B][T][H] -> vtg [B][H][T] (fp16 bits via short).
// ---------------------------------------------------------------------------
__global__ __launch_bounds__(256) void vtrans(
    const short* __restrict__ vh, short* __restrict__ vtg)
{
    __shared__ short tbuf[64][72];
    const int b  = blockIdx.z;
    const int t0 = blockIdx.x * 64;
    const int h0 = blockIdx.y * 64;
    const int tid = threadIdx.x;
    const size_t bo  = (size_t)b * T_ * H_;
    const size_t vbo = (size_t)b * H_ * T_;

    #pragma unroll
    for (int it = 0; it < 2; ++it) {
        const int u = tid + it * 256;
        const int r = u >> 3, c8 = u & 7;
        *(s16x8*)&tbuf[r][c8 * 8] =
            *(const s16x8*)&vh[bo + (size_t)(t0 + r) * H_ + h0 + c8 * 8];
    }
    __syncthreads();
    #pragma unroll
    for (int it = 0; it < 2; ++it) {
        const int u = tid + it * 256;
        const int t8 = u >> 6, hr = u & 63;
        s16x8 v;
        #pragma unroll
        for (int j = 0; j < 8; ++j) v[j] = tbuf[t8 * 8 + j][hr];
        *(s16x8*)&vtg[vbo + (size_t)(h0 + hr) * T_ + t0 + t8 * 8] = v;
    }
}

// ---------------------------------------------------------------------------
// Kernel 2: causal flash attention v5 — swapped QK^T (lane-local softmax),
// fp16 MFMA, double-buffered LDS, ONE barrier per round.
// grid 512 1D; rank = wg>>3, tile = rank<32 ? 63-rank : rank-32 (pairs on a
// CU sum to 63 rounds); batch = wg&7 (pins batch K/V to one XCD L2).
// 4 waves: rg=w>>1 (16 q rows), kp=w&1 (key-tile parity). 64 keys/round.
// ---------------------------------------------------------------------------
__global__ __launch_bounds__(256, 2) void attn_v5(
    const _Float16* __restrict__ qg, const _Float16* __restrict__ kg,
    const _Float16* __restrict__ vtg, float* __restrict__ out)
{
    __shared__ __align__(16) short Kbuf[2][64 * 128];   // 32 KB
    __shared__ __align__(16) short Vbuf[2][128 * 64];   // 32 KB
    __shared__ __align__(16) short Pl[4][16 * 40];      // 5 KB

    float* Ocmb = (float*)&Kbuf[0][0];   // [2][16][132] floats (aliased)
    float* Mcmb = (float*)&Vbuf[0][0];   // [2][16][2]   floats (aliased)

    const int tid  = threadIdx.x;
    const int lane = tid & 63;
    const int w    = tid >> 6;
    const int rg   = w >> 1;
    const int kp   = w & 1;
    const int lg   = lane >> 4;
    const int lc   = lane & 15;
    const int wg   = blockIdx.x;
    const int rank = wg >> 3;
    const int tile = (rank < 32) ? (63 - rank) : (rank - 32);
    const int b    = wg & 7;
    const int t0   = tile * TQA;

    const size_t bo  = (size_t)b * T_ * H_;
    const size_t vbo = (size_t)b * H_ * T_;

    // Q fragment (B-operand of swapped QK): lane lc holds q-row t0+rg*16+lc
    f16x8 qf[4];
    {
        const size_t qbase = bo + (size_t)(t0 + rg * 16 + lc) * H_;
        #pragma unroll
        for (int kc = 0; kc < 4; ++kc)
            qf[kc] = *(const f16x8*)(qg + qbase + kc * 32 + lg * 8);
    }

    f32x4 Oacc[8];
    #pragma unroll
    for (int ht = 0; ht < 8; ++ht) Oacc[ht] = (f32x4){0.f, 0.f, 0.f, 0.f};
    float m_run = -INFINITY;
    float l_run = 0.f;

    const int nt = tile + 1;              // 32-key tiles
    const int R  = (nt + 1) >> 1;         // rounds, 64 keys each

    f16x8 pf[8];                          // staged 32 KB / 256 threads

    // chunk c = tid + it*256 in [0,2048): c<1024 -> K (key=c>>4, slot=c&15,
    // global hc = slot^(key&7)); else V (h=c'>>3, slot=c'&7, k8=slot^((h>>1)&7))
    #define ISSUE_ST(rs0_)                                                    \
        _Pragma("unroll")                                                     \
        for (int it = 0; it < 8; ++it) {                                      \
            const int c = tid + it * 256;                                     \
            if (c < 1024) {                                                   \
                const int key = c >> 4, slot = c & 15;                        \
                const int hc = slot ^ (key & 7);                              \
                pf[it] = *(const f16x8*)(kg + bo                              \
                          + (size_t)((rs0_) + key) * H_ + hc * 8);            \
            } else {                                                          \
                const int cc = c - 1024;                                      \
                const int hh = cc >> 3, slot = cc & 7;                        \
                const int k8 = slot ^ ((hh >> 1) & 7);                        \
                pf[it] = *(const f16x8*)(vtg + vbo + (size_t)hh * T_          \
                          + (rs0_) + k8 * 8);                                 \
            }                                                                 \
        }

    #define WRITE_ST(bf_)                                                    \
        _Pragma("unroll")                                                     \
        for (int it = 0; it < 8; ++it) {                                      \
            const int c = tid + it * 256;                                     \
            if (c < 1024) {                                                   \
                const int key = c >> 4, slot = c & 15;                        \
                *(f16x8*)&Kbuf[bf_][key * 128 + slot * 8] = pf[it];           \
            } else {                                                          \
                const int cc = c - 1024;                                      \
                const int hh = cc >> 3, slot = cc & 7;                        \
                *(f16x8*)&Vbuf[bf_][hh * 64 + slot * 8] = pf[it];             \
            }                                                                 \
        }

    ISSUE_ST(0);

    for (int r = 0; r < R; ++r) {
        const int bf = r & 1;
        WRITE_ST(bf);                     // waits vmcnt on pf (compiler)
        __syncthreads();                  // buffer bf ready
        if (r + 1 < R) ISSUE_ST((r + 1) * 64);

        const int kt = 2 * r + kp;
        if (kt < nt) {
            // ---- S^T = K_tile @ Q^T : key-in-reg, qrow-in-lane ----
            f32x4 sfr[2];
            sfr[0] = (f32x4){0.f, 0.f, 0.f, 0.f};
            sfr[1] = (f32x4){0.f, 0.f, 0.f, 0.f};
            #pragma unroll
            for (int kc = 0; kc < 4; ++kc) {
                #pragma unroll
                for (int ct = 0; ct < 2; ++ct) {
                    const int key  = kp * 32 + ct * 16 + lc;   // local key row
                    const int slot = (kc * 4 + lg) ^ (key & 7);
                    const f16x8 ka = *(const f16x8*)&Kbuf[bf][key * 128 + slot * 8];
                    sfr[ct] = __builtin_amdgcn_mfma_f32_16x16x32_f16(ka, qf[kc], sfr[ct], 0, 0, 0);
                }
            }

            // ---- causal mask: key index is in-register now ----
            const int qrow_g = t0 + rg * 16 + lc;
            #pragma unroll
            for (int ct = 0; ct < 2; ++ct) {
                #pragma unroll
                for (int rr = 0; rr < 4; ++rr) {
                    const int key_g = kt * 32 + ct * 16 + lg * 4 + rr;
                    if (key_g > qrow_g) sfr[ct][rr] = -INFINITY;
                }
            }

            // ---- softmax: lane-local over 8 regs + 2 shfls across lg ----
            float pmax = sfr[0][0];
            #pragma unroll
            for (int ct = 0; ct < 2; ++ct)
                #pragma unroll
                for (int rr = 0; rr < 4; ++rr) pmax = fmaxf(pmax, sfr[ct][rr]);
            pmax = fmaxf(pmax, __shfl_xor(pmax, 16, 64));
            pmax = fmaxf(pmax, __shfl_xor(pmax, 32, 64));

            const float mnew = fmaxf(m_run, pmax);
            const float sc = __expf(m_run - mnew);
            m_run = mnew;

            float psum = 0.f;
            #pragma unroll
            for (int ct = 0; ct < 2; ++ct)
                #pragma unroll
                for (int rr = 0; rr < 4; ++rr) {
                    const float p = __expf(sfr[ct][rr] - mnew);
                    sfr[ct][rr] = p;
                    psum += p;
                }
            psum += __shfl_xor(psum, 16, 64);
            psum += __shfl_xor(psum, 32, 64);
            l_run = l_run * sc + psum;

            // ---- P -> LDS: rr are consecutive keys -> b64 packs ----
            #pragma unroll
            for (int ct = 0; ct < 2; ++ct) {
                f16x4 pk;
                #pragma unroll
                for (int rr = 0; rr < 4; ++rr) pk[rr] = (_Float16)sfr[ct][rr];
                *(f16x4*)&Pl[w][lc * 40 + ct * 16 + lg * 4] = pk;
            }

            // ---- rescale Oacc (redistribute sc to qrow = lg*4+rr) ----
            float scq[4];
            #pragma unroll
            for (int rr = 0; rr < 4; ++rr) scq[rr] = __shfl(sc, lg * 4 + rr, 64);
            #pragma unroll
            for (int ht = 0; ht < 8; ++ht)
                #pragma unroll
                for (int rr = 0; rr < 4; ++rr) Oacc[ht][rr] *= scq[rr];

            // ---- PV: A = P (qrow-major), B = V^T slice ----
            const f16x8 pa = *(const f16x8*)&Pl[w][lc * 40 + lg * 8];
            #pragma unroll
            for (int ht = 0; ht < 8; ++ht) {
                const int hh   = ht * 16 + lc;
                const int slot = (kp * 4 + lg) ^ ((hh >> 1) & 7);
                const f16x8 vb = *(const f16x8*)&Vbuf[bf][hh * 64 + slot * 8];
                Oacc[ht] = __builtin_amdgcn_mfma_f32_16x16x32_f16(pa, vb, Oacc[ht], 0, 0, 0);
            }
        }
    }

    __syncthreads();                      // all rounds done before aliasing

    // ---- pair combine: kp=1 publishes, kp=0 merges + writes ----
    if (kp == 1) {
        #pragma unroll
        for (int ht = 0; ht < 8; ++ht)
            #pragma unroll
            for (int rr = 0; rr < 4; ++rr)
                Ocmb[(size_t)(rg * 16 + lg * 4 + rr) * 132 + ht * 16 + lc] =
                    Oacc[ht][rr];
        if (lg == 0) {
            Mcmb[(rg * 16 + lc) * 2]     = m_run;
            Mcmb[(rg * 16 + lc) * 2 + 1] = l_run;
        }
    }
    __syncthreads();
    if (kp == 0) {
        const float m1 = Mcmb[(rg * 16 + lc) * 2];
        const float l1 = Mcmb[(rg * 16 + lc) * 2 + 1];
        const float M  = fmaxf(m_run, m1);
        const float a0 = __expf(m_run - M);       // exp(-inf)=0 safe
        const float a1 = __expf(m1 - M);
        const float inv = 1.f / (l_run * a0 + l1 * a1);
        const float f0 = a0 * inv, f1 = a1 * inv;
        float f0q[4], f1q[4];
        #pragma unroll
        for (int rr = 0; rr < 4; ++rr) {
            f0q[rr] = __shfl(f0, lg * 4 + rr, 64);
            f1q[rr] = __shfl(f1, lg * 4 + rr, 64);
        }
        float* ob = out + bo + (size_t)(t0 + rg * 16) * H_;
        #pragma unroll
        for (int ht = 0; ht < 8; ++ht)
            #pragma unroll
            for (int rr = 0; rr < 4; ++rr) {
                const float o1 =
                    Ocmb[(size_t)(rg * 16 + lg * 4 + rr) * 132 + ht * 16 + lc];
                ob[(size_t)(lg * 4 + rr) * H_ + ht * 16 + lc] =
                    Oacc[ht][rr] * f0q[rr] + o1 * f1q[rr];
            }
    }
}

// ---------------------------------------------------------------------------
extern "C" void kernel_launch(void* const* d_in, const int* in_sizes, int n_in,
                              void* d_out, int out_size, void* d_ws, size_t ws_size,
                              hipStream_t stream)
{
    const float* x  = (const float*)d_in[0];
    const float* Wq = (const float*)d_in[1];
    const float* bq = (const float*)d_in[2];
    const float* Wk = (const float*)d_in[3];
    const float* bk = (const float*)d_in[4];
    const float* Wv = (const float*)d_in[5];
    const float* bv = (const float*)d_in[6];
    float* out = (float*)d_out;

    const size_t SZ = (size_t)B_ * T_ * H_;     // 2M elems
    _Float16* qg = (_Float16*)d_ws;
    _Float16* kg = qg + SZ;
    _Float16* vg = kg + SZ;
    short* Wth   = (short*)(vg + SZ);            // [384][1024] bf16
    short* Wtl   = Wth + (size_t)384 * C_;
    _Float16* vtg = (_Float16*)(Wtl + (size_t)384 * C_);   // [B][H][T]

    wprep<<<dim3(384), dim3(256), 0, stream>>>(Wq, Wk, Wv, Wth, Wtl);
    gemm_proj<<<dim3(B_ * T_ / BM, 3), dim3(256), 0, stream>>>(
        x, Wth, Wtl, bq, bk, bv, qg, kg, vg);
    vtrans<<<dim3(T_ / 64, H_ / 64, B_), dim3(256), 0, stream>>>(
        (const short*)vg, (short*)vtg);
    attn_v5<<<dim3(512), dim3(256), 0, stream>>>(qg, kg, vtg, out);
}

// Round 8
// 84.570 us; speedup vs baseline: 2.1002x; 1.2231x over previous
//
#include <hip/hip_runtime.h>
#include <math.h>

#define B_ 8
#define T_ 2048
#define C_ 1024
#define H_ 128

#define TQA 32           // q rows per attention block (2 row-groups x 16)

#define GM 64            // gemm M-tile
#define GN 128           // gemm N-tile
#define GK 64            // gemm K-tile

typedef __attribute__((ext_vector_type(8))) short s16x8;
typedef __attribute__((ext_vector_type(4))) float f32x4;
typedef __attribute__((ext_vector_type(8))) _Float16 f16x8;
typedef __attribute__((ext_vector_type(4))) _Float16 f16x4;

// ---------------------------------------------------------------------------
// Kernel 0: W prep — transpose W[k][h] (q,k,v) into Wtf[n][k] fp16.
// ---------------------------------------------------------------------------
__global__ __launch_bounds__(256) void wprep(
    const float* __restrict__ Wq, const float* __restrict__ Wk,
    const float* __restrict__ Wv, _Float16* __restrict__ Wtf)
{
    const int n   = blockIdx.x;           // 0..383
    const int mat = n >> 7;
    const int h   = n & 127;
    const float* W = (mat == 0) ? Wq : (mat == 1) ? Wk : Wv;
    for (int k = threadIdx.x; k < C_; k += 256)
        Wtf[(size_t)n * C_ + k] = (_Float16)W[(size_t)k * H_ + h];
}

// ---------------------------------------------------------------------------
// Kernel 1: 2-term fp16 MFMA GEMM:  q = xh@W + xl@W  (x = xh+xl fp16 split,
// W single fp16 — W rounding 2^-11 matches the fp16 q/k output rounding).
// grid (256, 3): 64-row M-blocks x matrix; 768 blocks = exactly 3/CU.
// 256 threads = 4 waves (2x2), wave tile 32x64, acc[2][4] f32x4.
// LDS 32 KB: Ah/Al [64][64] fp16 + Bf [128][64] fp16, XOR-swizzled.
// ---------------------------------------------------------------------------
__global__ __launch_bounds__(256, 3) void gemm_proj(
    const float* __restrict__ x,
    const _Float16* __restrict__ Wtf,
    const float* __restrict__ bq, const float* __restrict__ bk,
    const float* __restrict__ bv,
    _Float16* __restrict__ qg, _Float16* __restrict__ kg,
    _Float16* __restrict__ vg)
{
    __shared__ _Float16 Ah[GM * GK];      // 8 KB
    __shared__ _Float16 Al[GM * GK];      // 8 KB
    __shared__ _Float16 Bf[GN * GK];      // 16 KB

    const int tid  = threadIdx.x;
    const int my   = blockIdx.y;
    const long m0  = (long)blockIdx.x * GM;
    const int lane = tid & 63;
    const int w    = tid >> 6;
    const int wr   = w >> 1, wc = w & 1;
    const int lg   = lane >> 4, lc = lane & 15;

    float4 xr[4];                         // prefetched x tile (16 floats)

    #define LOAD_X(k0)                                                        \
        _Pragma("unroll")                                                     \
        for (int it = 0; it < 4; ++it) {                                      \
            const int i  = tid + it * 256;                                    \
            const int r  = i >> 4;                                            \
            const int k4 = i & 15;                                            \
            xr[it] = *(const float4*)&x[(m0 + r) * C_ + (k0) + k4 * 4];       \
        }

    #define STORE_LDS(k0)                                                     \
        _Pragma("unroll")                                                     \
        for (int it = 0; it < 4; ++it) {                                      \
            const int i  = tid + it * 256;                                    \
            const int r  = i >> 4;                                            \
            const int k4 = i & 15;                                            \
            f16x4 hi4, lo4;                                                   \
            _Pragma("unroll")                                                 \
            for (int j = 0; j < 4; ++j) {                                     \
                const float f = ((const float*)&xr[it])[j];                   \
                const _Float16 h16 = (_Float16)f;                             \
                hi4[j] = h16;                                                 \
                lo4[j] = (_Float16)(f - (float)h16);                          \
            }                                                                 \
            const int off = r * 64 + (((k4 >> 1) ^ (r & 7)) << 3)             \
                          + ((k4 & 1) << 2);                                  \
            *(f16x4*)&Ah[off] = hi4;                                          \
            *(f16x4*)&Al[off] = lo4;                                          \
        }                                                                     \
        _Pragma("unroll")                                                     \
        for (int it = 0; it < 4; ++it) {                                      \
            const int i = tid + it * 256;                                     \
            const int r = i >> 3;                                             \
            const int s = i & 7;                                              \
            const size_t g = (size_t)(my * GN + r) * C_ + (k0) + s * 8;       \
            const int off = r * 64 + ((s ^ (r & 7)) << 3);                    \
            *(f16x8*)&Bf[off] = *(const f16x8*)&Wtf[g];                       \
        }

    f32x4 acc[2][4];
    #pragma unroll
    for (int m = 0; m < 2; ++m)
        #pragma unroll
        for (int n = 0; n < 4; ++n) acc[m][n] = (f32x4){0.f, 0.f, 0.f, 0.f};

    LOAD_X(0);
    STORE_LDS(0);
    __syncthreads();

    for (int kt = 0; kt < C_ / GK; ++kt) {
        if (kt < C_ / GK - 1) LOAD_X((kt + 1) * GK);

        #pragma unroll
        for (int kc = 0; kc < 2; ++kc) {
            f16x8 afh[2], afl[2], bf[4];
            #pragma unroll
            for (int m = 0; m < 2; ++m) {
                const int r = wr * 32 + m * 16 + lc;
                const int off = r * 64 + ((((kc << 2) + lg) ^ (r & 7)) << 3);
                afh[m] = *(const f16x8*)&Ah[off];
                afl[m] = *(const f16x8*)&Al[off];
            }
            #pragma unroll
            for (int n = 0; n < 4; ++n) {
                const int r = wc * 64 + n * 16 + lc;
                const int off = r * 64 + ((((kc << 2) + lg) ^ (r & 7)) << 3);
                bf[n] = *(const f16x8*)&Bf[off];
            }
            #pragma unroll
            for (int m = 0; m < 2; ++m)
                #pragma unroll
                for (int n = 0; n < 4; ++n) {
                    acc[m][n] = __builtin_amdgcn_mfma_f32_16x16x32_f16(afh[m], bf[n], acc[m][n], 0, 0, 0);
                    acc[m][n] = __builtin_amdgcn_mfma_f32_16x16x32_f16(afl[m], bf[n], acc[m][n], 0, 0, 0);
                }
        }
        __syncthreads();
        if (kt < C_ / GK - 1) {
            STORE_LDS((kt + 1) * GK);
            __syncthreads();
        }
    }

    const float* bias = (my == 0) ? bq : (my == 1) ? bk : bv;
    _Float16* og = (my == 0) ? qg : (my == 1) ? kg : vg;

    #pragma unroll
    for (int n = 0; n < 4; ++n) {
        const int h = wc * 64 + n * 16 + lc;
        const float bv_ = bias[h];
        #pragma unroll
        for (int m = 0; m < 2; ++m) {
            #pragma unroll
            for (int rr = 0; rr < 4; ++rr) {
                const long row = m0 + wr * 32 + m * 16 + lg * 4 + rr;
                og[(size_t)row * H_ + h] = (_Float16)(acc[m][n][rr] + bv_);
            }
        }
    }
}

// ---------------------------------------------------------------------------
// Kernel 1b: vtrans — vg [B][T][H] -> vtg [B][H][T] (fp16 bits via short).
// ---------------------------------------------------------------------------
__global__ __launch_bounds__(256) void vtrans(
    const short* __restrict__ vh, short* __restrict__ vtg)
{
    __shared__ short tbuf[64][72];
    const int b  = blockIdx.z;
    const int t0 = blockIdx.x * 64;
    const int h0 = blockIdx.y * 64;
    const int tid = threadIdx.x;
    const size_t bo  = (size_t)b * T_ * H_;
    const size_t vbo = (size_t)b * H_ * T_;

    #pragma unroll
    for (int it = 0; it < 2; ++it) {
        const int u = tid + it * 256;
        const int r = u >> 3, c8 = u & 7;
        *(s16x8*)&tbuf[r][c8 * 8] =
            *(const s16x8*)&vh[bo + (size_t)(t0 + r) * H_ + h0 + c8 * 8];
    }
    __syncthreads();
    #pragma unroll
    for (int it = 0; it < 2; ++it) {
        const int u = tid + it * 256;
        const int t8 = u >> 6, hr = u & 63;
        s16x8 v;
        #pragma unroll
        for (int j = 0; j < 8; ++j) v[j] = tbuf[t8 * 8 + j][hr];
        *(s16x8*)&vtg[vbo + (size_t)(h0 + hr) * T_ + t0 + t8 * 8] = v;
    }
}

// ---------------------------------------------------------------------------
// Kernel 2: causal flash attention v5 (unchanged from round 7).
// ---------------------------------------------------------------------------
__global__ __launch_bounds__(256, 2) void attn_v5(
    const _Float16* __restrict__ qg, const _Float16* __restrict__ kg,
    const _Float16* __restrict__ vtg, float* __restrict__ out)
{
    __shared__ __align__(16) short Kbuf[2][64 * 128];   // 32 KB
    __shared__ __align__(16) short Vbuf[2][128 * 64];   // 32 KB
    __shared__ __align__(16) short Pl[4][16 * 40];      // 5 KB

    float* Ocmb = (float*)&Kbuf[0][0];   // [32][132] floats (aliased)
    float* Mcmb = (float*)&Vbuf[0][0];   // [32][2]   floats (aliased)

    const int tid  = threadIdx.x;
    const int lane = tid & 63;
    const int w    = tid >> 6;
    const int rg   = w >> 1;
    const int kp   = w & 1;
    const int lg   = lane >> 4;
    const int lc   = lane & 15;
    const int wg   = blockIdx.x;
    const int rank = wg >> 3;
    const int tile = (rank < 32) ? (63 - rank) : (rank - 32);
    const int b    = wg & 7;
    const int t0   = tile * TQA;

    const size_t bo  = (size_t)b * T_ * H_;
    const size_t vbo = (size_t)b * H_ * T_;

    f16x8 qf[4];
    {
        const size_t qbase = bo + (size_t)(t0 + rg * 16 + lc) * H_;
        #pragma unroll
        for (int kc = 0; kc < 4; ++kc)
            qf[kc] = *(const f16x8*)(qg + qbase + kc * 32 + lg * 8);
    }

    f32x4 Oacc[8];
    #pragma unroll
    for (int ht = 0; ht < 8; ++ht) Oacc[ht] = (f32x4){0.f, 0.f, 0.f, 0.f};
    float m_run = -INFINITY;
    float l_run = 0.f;

    const int nt = tile + 1;
    const int R  = (nt + 1) >> 1;

    f16x8 pf[8];

    #define ISSUE_ST(rs0_)                                                    \
        _Pragma("unroll")                                                     \
        for (int it = 0; it < 8; ++it) {                                      \
            const int c = tid + it * 256;                                     \
            if (c < 1024) {                                                   \
                const int key = c >> 4, slot = c & 15;                        \
                const int hc = slot ^ (key & 7);                              \
                pf[it] = *(const f16x8*)(kg + bo                              \
                          + (size_t)((rs0_) + key) * H_ + hc * 8);            \
            } else {                                                          \
                const int cc = c - 1024;                                      \
                const int hh = cc >> 3, slot = cc & 7;                        \
                const int k8 = slot ^ ((hh >> 1) & 7);                        \
                pf[it] = *(const f16x8*)(vtg + vbo + (size_t)hh * T_          \
                          + (rs0_) + k8 * 8);                                 \
            }                                                                 \
        }

    #define WRITE_ST(bf_)                                                    \
        _Pragma("unroll")                                                     \
        for (int it = 0; it < 8; ++it) {                                      \
            const int c = tid + it * 256;                                     \
            if (c < 1024) {                                                   \
                const int key = c >> 4, slot = c & 15;                        \
                *(f16x8*)&Kbuf[bf_][key * 128 + slot * 8] = pf[it];           \
            } else {                                                          \
                const int cc = c - 1024;                                      \
                const int hh = cc >> 3, slot = cc & 7;                        \
                *(f16x8*)&Vbuf[bf_][hh * 64 + slot * 8] = pf[it];             \
            }                                                                 \
        }

    ISSUE_ST(0);

    for (int r = 0; r < R; ++r) {
        const int bf = r & 1;
        WRITE_ST(bf);
        __syncthreads();
        if (r + 1 < R) ISSUE_ST((r + 1) * 64);

        const int kt = 2 * r + kp;
        if (kt < nt) {
            f32x4 sfr[2];
            sfr[0] = (f32x4){0.f, 0.f, 0.f, 0.f};
            sfr[1] = (f32x4){0.f, 0.f, 0.f, 0.f};
            #pragma unroll
            for (int kc = 0; kc < 4; ++kc) {
                #pragma unroll
                for (int ct = 0; ct < 2; ++ct) {
                    const int key  = kp * 32 + ct * 16 + lc;
                    const int slot = (kc * 4 + lg) ^ (key & 7);
                    const f16x8 ka = *(const f16x8*)&Kbuf[bf][key * 128 + slot * 8];
                    sfr[ct] = __builtin_amdgcn_mfma_f32_16x16x32_f16(ka, qf[kc], sfr[ct], 0, 0, 0);
                }
            }

            const int qrow_g = t0 + rg * 16 + lc;
            #pragma unroll
            for (int ct = 0; ct < 2; ++ct) {
                #pragma unroll
                for (int rr = 0; rr < 4; ++rr) {
                    const int key_g = kt * 32 + ct * 16 + lg * 4 + rr;
                    if (key_g > qrow_g) sfr[ct][rr] = -INFINITY;
                }
            }

            float pmax = sfr[0][0];
            #pragma unroll
            for (int ct = 0; ct < 2; ++ct)
                #pragma unroll
                for (int rr = 0; rr < 4; ++rr) pmax = fmaxf(pmax, sfr[ct][rr]);
            pmax = fmaxf(pmax, __shfl_xor(pmax, 16, 64));
            pmax = fmaxf(pmax, __shfl_xor(pmax, 32, 64));

            const float mnew = fmaxf(m_run, pmax);
            const float sc = __expf(m_run - mnew);
            m_run = mnew;

            float psum = 0.f;
            #pragma unroll
            for (int ct = 0; ct < 2; ++ct)
                #pragma unroll
                for (int rr = 0; rr < 4; ++rr) {
                    const float p = __expf(sfr[ct][rr] - mnew);
                    sfr[ct][rr] = p;
                    psum += p;
                }
            psum += __shfl_xor(psum, 16, 64);
            psum += __shfl_xor(psum, 32, 64);
            l_run = l_run * sc + psum;

            #pragma unroll
            for (int ct = 0; ct < 2; ++ct) {
                f16x4 pk;
                #pragma unroll
                for (int rr = 0; rr < 4; ++rr) pk[rr] = (_Float16)sfr[ct][rr];
                *(f16x4*)&Pl[w][lc * 40 + ct * 16 + lg * 4] = pk;
            }

            float scq[4];
            #pragma unroll
            for (int rr = 0; rr < 4; ++rr) scq[rr] = __shfl(sc, lg * 4 + rr, 64);
            #pragma unroll
            for (int ht = 0; ht < 8; ++ht)
                #pragma unroll
                for (int rr = 0; rr < 4; ++rr) Oacc[ht][rr] *= scq[rr];

            const f16x8 pa = *(const f16x8*)&Pl[w][lc * 40 + lg * 8];
            #pragma unroll
            for (int ht = 0; ht < 8; ++ht) {
                const int hh   = ht * 16 + lc;
                const int slot = (kp * 4 + lg) ^ ((hh >> 1) & 7);
                const f16x8 vb = *(const f16x8*)&Vbuf[bf][hh * 64 + slot * 8];
                Oacc[ht] = __builtin_amdgcn_mfma_f32_16x16x32_f16(pa, vb, Oacc[ht], 0, 0, 0);
            }
        }
    }

    __syncthreads();

    if (kp == 1) {
        #pragma unroll
        for (int ht = 0; ht < 8; ++ht)
            #pragma unroll
            for (int rr = 0; rr < 4; ++rr)
                Ocmb[(size_t)(rg * 16 + lg * 4 + rr) * 132 + ht * 16 + lc] =
                    Oacc[ht][rr];
        if (lg == 0) {
            Mcmb[(rg * 16 + lc) * 2]     = m_run;
            Mcmb[(rg * 16 + lc) * 2 + 1] = l_run;
        }
    }
    __syncthreads();
    if (kp == 0) {
        const float m1 = Mcmb[(rg * 16 + lc) * 2];
        const float l1 = Mcmb[(rg * 16 + lc) * 2 + 1];
        const float M  = fmaxf(m_run, m1);
        const float a0 = __expf(m_run - M);
        const float a1 = __expf(m1 - M);
        const float inv = 1.f / (l_run * a0 + l1 * a1);
        const float f0 = a0 * inv, f1 = a1 * inv;
        float f0q[4], f1q[4];
        #pragma unroll
        for (int rr = 0; rr < 4; ++rr) {
            f0q[rr] = __shfl(f0, lg * 4 + rr, 64);
            f1q[rr] = __shfl(f1, lg * 4 + rr, 64);
        }
        float* ob = out + bo + (size_t)(t0 + rg * 16) * H_;
        #pragma unroll
        for (int ht = 0; ht < 8; ++ht)
            #pragma unroll
            for (int rr = 0; rr < 4; ++rr) {
                const float o1 =
                    Ocmb[(size_t)(rg * 16 + lg * 4 + rr) * 132 + ht * 16 + lc];
                ob[(size_t)(lg * 4 + rr) * H_ + ht * 16 + lc] =
                    Oacc[ht][rr] * f0q[rr] + o1 * f1q[rr];
            }
    }
}

// ---------------------------------------------------------------------------
extern "C" void kernel_launch(void* const* d_in, const int* in_sizes, int n_in,
                              void* d_out, int out_size, void* d_ws, size_t ws_size,
                              hipStream_t stream)
{
    const float* x  = (const float*)d_in[0];
    const float* Wq = (const float*)d_in[1];
    const float* bq = (const float*)d_in[2];
    const float* Wk = (const float*)d_in[3];
    const float* bk = (const float*)d_in[4];
    const float* Wv = (const float*)d_in[5];
    const float* bv = (const float*)d_in[6];
    float* out = (float*)d_out;

    const size_t SZ = (size_t)B_ * T_ * H_;     // 2M elems
    _Float16* qg  = (_Float16*)d_ws;
    _Float16* kg  = qg + SZ;
    _Float16* vg  = kg + SZ;
    _Float16* vtg = vg + SZ;                     // [B][H][T]
    _Float16* Wtf = vtg + SZ;                    // [384][1024]

    wprep<<<dim3(384), dim3(256), 0, stream>>>(Wq, Wk, Wv, Wtf);
    gemm_proj<<<dim3(B_ * T_ / GM, 3), dim3(256), 0, stream>>>(
        x, Wtf, bq, bk, bv, qg, kg, vg);
    vtrans<<<dim3(T_ / 64, H_ / 64, B_), dim3(256), 0, stream>>>(
        (const short*)vg, (short*)vtg);
    attn_v5<<<dim3(512), dim3(256), 0, stream>>>(qg, kg, vtg, out);
}